// Round 21
// baseline (91.341 us; speedup 1.0000x reference)
//
#include <hip/hip_runtime.h>

// GraphUnetPool: scores = sigmoid(h@w+b); top-k (k=N/2) by exact rank-count;
// new_h = h[idx]*values; un_g = (g@g)[idx][:,idx] via per-row LDS 2-path counting.
// R21 = R20 with the pk/desc2 workspace overlap fixed (caused R20's OOB fault).
// pk[p]=(v<<16)|rank[v] 1-line scatter, ILP-4 edge batching; desc2[v]=offs|deg<<32
// built in scan (no scattered desc writes); 1 random 8B load per first-hop stage.

typedef unsigned long long u64;
typedef unsigned int u32;
typedef float f32x4 __attribute__((ext_vector_type(4)));   // native vec for nt-store

__device__ __forceinline__ void nt_store4(float* p, float x, float y, float z, float w) {
    f32x4 v = { x, y, z, w };
    __builtin_nontemporal_store(v, (f32x4*)p);
}

// ---- node1: scores (1 wave/row) + zero rankcnt/deg + edge_attr ones ----
__global__ void fused_scores(const float* __restrict__ h, const float* __restrict__ w,
                             const float* __restrict__ b, u64* __restrict__ keys,
                             int* __restrict__ zerobuf, float* __restrict__ ones_out,
                             int N, int n4) {
    int g = blockIdx.x * blockDim.x + threadIdx.x;
    if (g < 2 * N) zerobuf[g] = 0;              // rankcnt (N) + deg (N), adjacent
    if (g < n4) nt_store4(ones_out + (size_t)g * 4, 1.f, 1.f, 1.f, 1.f);
    int wave = g >> 6;
    int lane = threadIdx.x & 63;
    if (wave >= N) return;
    const float4 a = ((const float4*)(h + (size_t)wave * 256))[lane];
    const float4 c = ((const float4*)w)[lane];
    float s = a.x * c.x + a.y * c.y + a.z * c.z + a.w * c.w;
    #pragma unroll
    for (int off = 32; off; off >>= 1) s += __shfl_xor(s, off);
    if (lane == 0) {
        s += b[0];
        float sc = 1.0f / (1.0f + expf(-s));
        keys[wave] = ((u64)__float_as_uint(sc) << 32) | (u32)(~wave);  // ties: lower idx
    }
}

// ---- node2: rank (1024-key LDS tiles, 1 elem/thread) + degree hist ----
__global__ void rank_hist(const u64* __restrict__ keys, int* __restrict__ rankcnt,
                          const int* __restrict__ ei0, int* __restrict__ deg,
                          int N, int E, int nrank) {
    __shared__ u64 lk[1024];
    int b = blockIdx.x, tid = threadIdx.x;
    if (b < nrank) {
        int ngroups = N >> 8;                   // element groups of 256
        int chunk = b / ngroups;                // 1024-key chunks
        int elg = b % ngroups;
        int base = chunk << 10;
        #pragma unroll
        for (int j = 0; j < 4; ++j) lk[tid + (j << 8)] = keys[base + tid + (j << 8)];
        __syncthreads();
        int el = (elg << 8) + tid;
        u64 mk = keys[el];
        int cnt = 0;
        #pragma unroll 16
        for (int i = 0; i < 1024; ++i) cnt += (lk[i] > mk) ? 1 : 0;
        atomicAdd(&rankcnt[el], cnt);
    } else {
        int e0 = ((b - nrank) << 10) + tid;     // 4 edges/thread
        #pragma unroll
        for (int j = 0; j < 4; ++j) {
            int e = e0 + (j << 8);
            if (e < E) atomicAdd(&deg[ei0[e]], 1);
        }
    }
}

// ---- node3: select + CSR scan; scan also emits desc2[v] = offs | deg<<32 ----
__global__ void select_scan(const u64* __restrict__ keys, const int* __restrict__ rankcnt,
                            const int* __restrict__ batch, int* __restrict__ idx_list,
                            float* __restrict__ val_list, int* __restrict__ rank,
                            float* __restrict__ out_idx, float* __restrict__ out_batch,
                            const int* __restrict__ deg, int* __restrict__ offs,
                            int* __restrict__ cursor, u64* __restrict__ desc2,
                            int N, int kN) {
    __shared__ int part[1024];
    int b = blockIdx.x, t = threadIdx.x;
    int nsel = N >> 10;                         // select blocks (1024 thr each)
    if (b < nsel) {
        int i = (b << 10) + t;
        int r = rankcnt[i];
        rank[i] = (r < kN) ? r : kN;            // kN = discard marker
        if (r < kN) {
            idx_list[r] = i;
            val_list[r] = __uint_as_float((u32)(keys[i] >> 32));
            out_idx[r] = (float)i;
            out_batch[r] = (float)batch[i];
        }
    } else {
        int per = N >> 10;                      // 8 per thread
        int base = t * per;
        int loc[8];
        int s = 0;
        #pragma unroll
        for (int j = 0; j < 8; ++j) { if (j < per) { loc[j] = s; s += deg[base + j]; } }
        part[t] = s;
        __syncthreads();
        for (int d = 1; d < 1024; d <<= 1) {
            int v = (t >= d) ? part[t - d] : 0;
            __syncthreads();
            part[t] += v;
            __syncthreads();
        }
        int excl = (t == 0) ? 0 : part[t - 1];
        #pragma unroll
        for (int j = 0; j < 8; ++j) {
            if (j < per) {
                int o = excl + loc[j];
                int dv = deg[base + j];
                offs[base + j] = o;
                cursor[(base + j) << 4] = o;    // padded: 1 counter / 64B line
                desc2[base + j] = (u64)(u32)o | ((u64)(u32)dv << 32);
            }
        }
        if (t == 1023) offs[N] = part[1023];
    }
}

// ---- node4: new_h + ILP-4 scatter of pk[p]=(v<<16)|rank[v] ----
__global__ void newh_scatter(const float* __restrict__ h, const int* __restrict__ idx_list,
                             const float* __restrict__ val_list, float* __restrict__ out_newh,
                             const int* __restrict__ ei0, const int* __restrict__ ei1,
                             int* __restrict__ cursor, const int* __restrict__ rank,
                             u32* __restrict__ pk, int kN, int E) {
    int b = blockIdx.x, tid = threadIdx.x;
    int nnewh = kN >> 2;                        // 4 waves/block
    if (b < nnewh) {
        int wave = (b << 2) + (tid >> 6);
        int lane = tid & 63;
        int i = idx_list[wave];
        float v = val_list[wave];
        float4 a = ((const float4*)(h + (size_t)i * 256))[lane];
        nt_store4(out_newh + (size_t)wave * 256 + lane * 4,
                  a.x * v, a.y * v, a.z * v, a.w * v);
    } else {
        int e0 = ((b - nnewh) << 10) + tid;     // block covers 1024 edges, 4/thread
        int us[4], vs[4], ps[4];
        #pragma unroll
        for (int j = 0; j < 4; ++j) {
            int e = e0 + (j << 8);
            us[j] = (e < E) ? ei0[e] : -1;
            vs[j] = (e < E) ? ei1[e] : 0;
        }
        #pragma unroll
        for (int j = 0; j < 4; ++j)             // 4 independent atomics in flight
            ps[j] = (us[j] >= 0) ? atomicAdd(&cursor[us[j] << 4], 1) : -1;
        #pragma unroll
        for (int j = 0; j < 4; ++j)
            if (ps[j] >= 0) pk[ps[j]] = ((u32)vs[j] << 16) | (u32)rank[vs[j]];
    }
}

// ---- node5: 2-path accumulation; staging = pk + desc2 (1 random 8B load);
//      full-coverage 16-deep ILP gather; discard-filtered LDS atomics ----
__global__ void paths_row_kernel(const int* __restrict__ idx_list, const int* __restrict__ offs,
                                 const u64* __restrict__ desc2, const u32* __restrict__ pk,
                                 float* __restrict__ ung, int kN) {
    extern __shared__ float row[];              // kN floats; then toff[256], tlen[256]
    int* toff = (int*)(row + kN);
    int* tlen = toff + 256;
    int tid = threadIdx.x;
    float4* row4 = (float4*)row;
    float4 z4 = make_float4(0.f, 0.f, 0.f, 0.f);
    for (int i = tid; i < (kN >> 2); i += 256) row4[i] = z4;
    __syncthreads();
    int u = idx_list[blockIdx.x];
    int s0 = offs[u], s1 = offs[u + 1];
    int nf = s1 - s0;
    int wid = tid >> 6;                         // wave 0..3
    int lane = tid & 63;
    u32 ukN = (u32)kN;
    for (int fb = 0; fb < nf; fb += 256) {
        int nt = min(256, nf - fb);
        if (tid < nt) {
            u32 val = pk[s0 + fb + tid];        // coalesced 4B stage
            u64 d2 = desc2[val >> 16];          // ONE random 8B load
            toff[tid] = (int)(u32)d2;
            tlen[tid] = (int)(d2 >> 32);
        }
        __syncthreads();
        // full coverage: rounds of 64 segments; wave wid owns 16 consecutive.
        for (int base = 0; base < nt; base += 64) {
            u32 va[16];
            #pragma unroll
            for (int k = 0; k < 16; ++k) {
                int f = base + (wid << 4) + k;
                va[k] = ukN;
                if (f < nt) {
                    int t0 = toff[f], L = tlen[f];
                    if (lane < L) va[k] = pk[t0 + lane] & 0xFFFFu;
                }
            }
            #pragma unroll
            for (int k = 0; k < 16; ++k)
                if (va[k] < ukN) atomicAdd(&row[va[k]], 1.0f);
            #pragma unroll
            for (int k = 0; k < 16; ++k) {      // rare tail: deg > 64
                int f = base + (wid << 4) + k;
                if (f < nt) {
                    int t0 = toff[f], L = tlen[f];
                    for (int q = lane + 64; q < L; q += 64) {
                        u32 r = pk[t0 + q] & 0xFFFFu;
                        if (r < ukN) atomicAdd(&row[r], 1.0f);
                    }
                }
            }
        }
        __syncthreads();
    }
    float* dst = ung + (size_t)blockIdx.x * kN;
    for (int i = tid; i < (kN >> 2); i += 256) {
        float4 v = row4[i];
        nt_store4(dst + (size_t)i * 4, v.x, v.y, v.z, v.w);
    }
}

extern "C" void kernel_launch(void* const* d_in, const int* in_sizes, int n_in,
                              void* d_out, int out_size, void* d_ws, size_t ws_size,
                              hipStream_t stream) {
    const float* h = (const float*)d_in[0];
    const int* ei = (const int*)d_in[1];            // [2,E] flat: ei0 = ei, ei1 = ei+E
    const int* batch = (const int*)d_in[3];
    const float* pw = (const float*)d_in[4];
    const float* pb = (const float*)d_in[5];

    int N = in_sizes[3];        // 8192
    int E = in_sizes[1] / 2;    // 262144
    int kN = N / 2;
    if (kN < 2) kN = 2;

    float* out = (float*)d_out;
    float* out_newh = out;                              // kN*256
    float* out_ung = out_newh + (size_t)kN * 256;       // kN*kN
    float* out_ea = out_ung + (size_t)kN * kN;          // E
    float* out_nb = out_ea + E;                         // kN
    float* out_idx = out_nb + kN;                       // kN

    // Non-overlapping workspace layout (R20's pk/desc2 overlap caused OOB fault):
    char* ws = (char*)d_ws;
    u64* keys    = (u64*)(ws + 0);          // [0,       65536)
    int* rankcnt = (int*)(ws + 65536);      // [65536,   98304)  zeroed w/ deg
    int* deg     = (int*)(ws + 98304);      // [98304,  131072)
    int* idx_list= (int*)(ws + 131072);     // [131072, 147456)
    float* vals  = (float*)(ws + 147456);   // [147456, 163840)
    int* rank    = (int*)(ws + 163840);     // [163840, 196608)
    int* offs    = (int*)(ws + 196608);     // [196608, 229380)
    int* cursor  = (int*)(ws + 262144);     // [262144, 786432)  padded 64B stride
    u32* pk      = (u32*)(ws + 786432);     // [786432, 1835008) 1 MB payload
    u64* desc2   = (u64*)(ws + 1835008);    // [1835008, 1900544) 64 KB

    // node1: scores + zero(rankcnt,deg) + ones(edge_attr)
    fused_scores<<<(N * 64 + 255) / 256, 256, 0, stream>>>(h, pw, pb, keys, rankcnt,
                                                           out_ea, N, E / 4);
    // node2: rank counting (1024-key LDS tiles, 1 elem/thread) + degree histogram
    int nrank = (N >> 10) * (N >> 8);
    int nhist = (E + 1023) / 1024;
    rank_hist<<<nrank + nhist, 256, 0, stream>>>(keys, rankcnt, ei, deg, N, E, nrank);
    // node3: select + scan (emits offs, padded cursor, desc2)
    select_scan<<<(N >> 10) + 1, 1024, 0, stream>>>(keys, rankcnt, batch, idx_list, vals,
                                                    rank, out_idx, out_nb, deg, offs,
                                                    cursor, desc2, N, kN);
    // node4: new_h + ILP-4 packed scatter
    newh_scatter<<<(kN >> 2) + (E >> 10), 256, 0, stream>>>(h, idx_list, vals, out_newh,
                                                            ei, ei + E, cursor, rank,
                                                            pk, kN, E);
    // node5: per-row 2-path accumulation
    paths_row_kernel<<<kN, 256, (size_t)kN * 4 + 2048, stream>>>(idx_list, offs, desc2,
                                                                 pk, out_ung, kN);
}

// Round 22
// 75.891 us; speedup vs baseline: 1.2036x; 1.2036x over previous
//
#include <hip/hip_runtime.h>

// GraphUnetPool: scores = sigmoid(h@w+b); top-k (k=N/2) by exact rank-count;
// new_h = h[idx]*values; un_g = (g@g)[idx][:,idx] via per-row LDS 2-path counting.
// R22 = R17 (best: 83.4us) + padded cursor (1 counter / 64B line) + coverage-safe
// interleaved gather mapping (f = f0 + wid + 4k, f0 += 64).

typedef unsigned long long u64;
typedef unsigned int u32;
typedef float f32x4 __attribute__((ext_vector_type(4)));   // native vec for nt-store

__device__ __forceinline__ void nt_store4(float* p, float x, float y, float z, float w) {
    f32x4 v = { x, y, z, w };
    __builtin_nontemporal_store(v, (f32x4*)p);
}

// ---- node1: scores (1 wave/row) + zero rankcnt/deg + edge_attr ones ----
__global__ void fused_scores(const float* __restrict__ h, const float* __restrict__ w,
                             const float* __restrict__ b, u64* __restrict__ keys,
                             int* __restrict__ zerobuf, float* __restrict__ ones_out,
                             int N, int n4) {
    int g = blockIdx.x * blockDim.x + threadIdx.x;
    if (g < 2 * N) zerobuf[g] = 0;              // rankcnt (N) + deg (N), adjacent
    if (g < n4) nt_store4(ones_out + (size_t)g * 4, 1.f, 1.f, 1.f, 1.f);
    int wave = g >> 6;
    int lane = threadIdx.x & 63;
    if (wave >= N) return;
    const float4 a = ((const float4*)(h + (size_t)wave * 256))[lane];
    const float4 c = ((const float4*)w)[lane];
    float s = a.x * c.x + a.y * c.y + a.z * c.z + a.w * c.w;
    #pragma unroll
    for (int off = 32; off; off >>= 1) s += __shfl_xor(s, off);
    if (lane == 0) {
        s += b[0];
        float sc = 1.0f / (1.0f + expf(-s));
        keys[wave] = ((u64)__float_as_uint(sc) << 32) | (u32)(~wave);  // ties: lower idx
    }
}

// ---- node2: rank (1024-key LDS tiles, 1 elem/thread) + degree hist ----
__global__ void rank_hist(const u64* __restrict__ keys, int* __restrict__ rankcnt,
                          const int* __restrict__ ei0, int* __restrict__ deg,
                          int N, int E, int nrank) {
    __shared__ u64 lk[1024];
    int b = blockIdx.x, tid = threadIdx.x;
    if (b < nrank) {
        int ngroups = N >> 8;                   // element groups of 256
        int chunk = b / ngroups;                // 1024-key chunks
        int elg = b % ngroups;
        int base = chunk << 10;
        #pragma unroll
        for (int j = 0; j < 4; ++j) lk[tid + (j << 8)] = keys[base + tid + (j << 8)];
        __syncthreads();
        int el = (elg << 8) + tid;
        u64 mk = keys[el];
        int cnt = 0;
        #pragma unroll 16
        for (int i = 0; i < 1024; ++i) cnt += (lk[i] > mk) ? 1 : 0;
        atomicAdd(&rankcnt[el], cnt);
    } else {
        int e0 = ((b - nrank) << 10) + tid;     // 4 edges/thread
        #pragma unroll
        for (int j = 0; j < 4; ++j) {
            int e = e0 + (j << 8);
            if (e < E) atomicAdd(&deg[ei0[e]], 1);
        }
    }
}

// ---- node3: select (rank scatter, outputs idx/batch) + CSR exclusive scan ----
// cursor PADDED: one counter per 64B line (index u<<4).
__global__ void select_scan(const u64* __restrict__ keys, const int* __restrict__ rankcnt,
                            const int* __restrict__ batch, int* __restrict__ idx_list,
                            float* __restrict__ val_list, int* __restrict__ rank,
                            float* __restrict__ out_idx, float* __restrict__ out_batch,
                            const int* __restrict__ deg, int* __restrict__ offs,
                            int* __restrict__ cursor, int N, int kN) {
    __shared__ int part[1024];
    int b = blockIdx.x, t = threadIdx.x;
    int nsel = N >> 10;                         // select blocks (1024 thr each)
    if (b < nsel) {
        int i = (b << 10) + t;
        int r = rankcnt[i];
        rank[i] = (r < kN) ? r : kN;            // kN = discard marker
        if (r < kN) {
            idx_list[r] = i;
            val_list[r] = __uint_as_float((u32)(keys[i] >> 32));
            out_idx[r] = (float)i;
            out_batch[r] = (float)batch[i];
        }
    } else {
        int per = N >> 10;                      // 8 per thread
        int base = t * per;
        int loc[8];
        int s = 0;
        #pragma unroll
        for (int j = 0; j < 8; ++j) { if (j < per) { loc[j] = s; s += deg[base + j]; } }
        part[t] = s;
        __syncthreads();
        for (int d = 1; d < 1024; d <<= 1) {
            int v = (t >= d) ? part[t - d] : 0;
            __syncthreads();
            part[t] += v;
            __syncthreads();
        }
        int excl = (t == 0) ? 0 : part[t - 1];
        #pragma unroll
        for (int j = 0; j < 8; ++j) {
            if (j < per) {
                int o = excl + loc[j];
                offs[base + j] = o;
                cursor[(base + j) << 4] = o;    // padded: 1 counter / 64B line
            }
        }
        if (t == 1023) offs[N] = part[1023];
    }
}

// ---- node4: new_h + scatter with packed 2-hop descriptors (R17 shape) ----
// Slot p (edge u->v): desc[p] = {offs[v], deg[v]}, nbrrank[p] = rank[v].
__global__ void newh_scatter(const float* __restrict__ h, const int* __restrict__ idx_list,
                             const float* __restrict__ val_list, float* __restrict__ out_newh,
                             const int* __restrict__ ei0, const int* __restrict__ ei1,
                             int* __restrict__ cursor, const int* __restrict__ offs,
                             const int* __restrict__ deg, const int* __restrict__ rank,
                             int2* __restrict__ desc, int* __restrict__ nbrrank,
                             int kN, int E) {
    int b = blockIdx.x, tid = threadIdx.x;
    int nnewh = kN >> 2;                        // 4 waves/block
    if (b < nnewh) {
        int wave = (b << 2) + (tid >> 6);
        int lane = tid & 63;
        int i = idx_list[wave];
        float v = val_list[wave];
        float4 a = ((const float4*)(h + (size_t)i * 256))[lane];
        nt_store4(out_newh + (size_t)wave * 256 + lane * 4,
                  a.x * v, a.y * v, a.z * v, a.w * v);
    } else {
        int e = ((b - nnewh) << 8) + tid;       // 1 edge/thread (max TLP)
        if (e < E) {
            int u = ei0[e], v = ei1[e];
            int p = atomicAdd(&cursor[u << 4], 1);
            desc[p] = make_int2(offs[v], deg[v]);
            nbrrank[p] = rank[v];
        }
    }
}

// ---- node5: 2-path accumulation; interleaved 16-deep ILP gather (all waves
//      active at small nf, full coverage for any nf); filtered LDS atomics ----
__global__ void paths_row_kernel(const int* __restrict__ idx_list, const int* __restrict__ offs,
                                 const int2* __restrict__ desc, const int* __restrict__ nbrrank,
                                 float* __restrict__ ung, int kN) {
    extern __shared__ float row[];              // kN floats; then toff[256], tlen[256]
    int* toff = (int*)(row + kN);
    int* tlen = toff + 256;
    int tid = threadIdx.x;
    float4* row4 = (float4*)row;
    float4 z4 = make_float4(0.f, 0.f, 0.f, 0.f);
    for (int i = tid; i < (kN >> 2); i += 256) row4[i] = z4;
    __syncthreads();
    int u = idx_list[blockIdx.x];
    int s0 = offs[u], s1 = offs[u + 1];
    int nf = s1 - s0;
    int wid = tid >> 6;                         // wave 0..3
    int lane = tid & 63;
    for (int fb = 0; fb < nf; fb += 256) {
        int nt = min(256, nf - fb);
        if (tid < nt) {
            int2 dd = desc[s0 + fb + tid];      // coalesced 8B descriptor stage
            toff[tid] = dd.x; tlen[tid] = dd.y;
        }
        __syncthreads();
        // interleaved: f = f0 + wid + 4k; f0 strides 64 -> covers any nt,
        // all 4 waves active whenever nt >= 4.
        for (int f0 = 0; f0 < nt; f0 += 64) {
            int va[16];
            #pragma unroll
            for (int k = 0; k < 16; ++k) {
                int f = f0 + wid + (k << 2);
                va[k] = kN;
                if (f < nt) {
                    int t0 = toff[f], L = tlen[f];
                    if (lane < L) va[k] = nbrrank[t0 + lane];
                }
            }
            #pragma unroll
            for (int k = 0; k < 16; ++k)
                if (va[k] < kN) atomicAdd(&row[va[k]], 1.0f);
            #pragma unroll
            for (int k = 0; k < 16; ++k) {      // rare tail: deg > 64
                int f = f0 + wid + (k << 2);
                if (f < nt) {
                    int t0 = toff[f], L = tlen[f];
                    for (int q = lane + 64; q < L; q += 64) {
                        int r = nbrrank[t0 + q];
                        if (r < kN) atomicAdd(&row[r], 1.0f);
                    }
                }
            }
        }
        __syncthreads();
    }
    float* dst = ung + (size_t)blockIdx.x * kN;
    for (int i = tid; i < (kN >> 2); i += 256) {
        float4 v = row4[i];
        nt_store4(dst + (size_t)i * 4, v.x, v.y, v.z, v.w);
    }
}

extern "C" void kernel_launch(void* const* d_in, const int* in_sizes, int n_in,
                              void* d_out, int out_size, void* d_ws, size_t ws_size,
                              hipStream_t stream) {
    const float* h = (const float*)d_in[0];
    const int* ei = (const int*)d_in[1];            // [2,E] flat: ei0 = ei, ei1 = ei+E
    const int* batch = (const int*)d_in[3];
    const float* pw = (const float*)d_in[4];
    const float* pb = (const float*)d_in[5];

    int N = in_sizes[3];        // 8192
    int E = in_sizes[1] / 2;    // 262144
    int kN = N / 2;
    if (kN < 2) kN = 2;

    float* out = (float*)d_out;
    float* out_newh = out;                              // kN*256
    float* out_ung = out_newh + (size_t)kN * 256;       // kN*kN
    float* out_ea = out_ung + (size_t)kN * kN;          // E
    float* out_nb = out_ea + E;                         // kN
    float* out_idx = out_nb + kN;                       // kN

    // Non-overlapping workspace layout:
    char* ws = (char*)d_ws;
    u64* keys    = (u64*)(ws + 0);          // [0,       65536)
    int* rankcnt = (int*)(ws + 65536);      // [65536,   98304)  zeroed w/ deg
    int* deg     = (int*)(ws + 98304);      // [98304,  131072)
    int* idx_list= (int*)(ws + 131072);     // [131072, 147456)
    float* vals  = (float*)(ws + 147456);   // [147456, 163840)
    int* rank    = (int*)(ws + 163840);     // [163840, 196608)
    int* offs    = (int*)(ws + 196608);     // [196608, 229380)
    int* cursor  = (int*)(ws + 262144);     // [262144, 786432)  padded 64B stride
    int2* desc   = (int2*)(ws + 786432);    // [786432, 2883584) 2 MB
    int* nbrrank = (int*)(ws + 2883584);    // [2883584, 3932160) 1 MB

    // node1: scores + zero(rankcnt,deg) + ones(edge_attr)
    fused_scores<<<(N * 64 + 255) / 256, 256, 0, stream>>>(h, pw, pb, keys, rankcnt,
                                                           out_ea, N, E / 4);
    // node2: rank counting (1024-key LDS tiles, 1 elem/thread) + degree histogram
    int nrank = (N >> 10) * (N >> 8);
    int nhist = (E + 1023) / 1024;
    rank_hist<<<nrank + nhist, 256, 0, stream>>>(keys, rankcnt, ei, deg, N, E, nrank);
    // node3: select + scan (padded cursor)
    select_scan<<<(N >> 10) + 1, 1024, 0, stream>>>(keys, rankcnt, batch, idx_list, vals,
                                                    rank, out_idx, out_nb, deg, offs,
                                                    cursor, N, kN);
    // node4: new_h + desc/nbrrank scatter (1 edge/thread TLP)
    newh_scatter<<<(kN >> 2) + (E >> 8), 256, 0, stream>>>(h, idx_list, vals, out_newh,
                                                           ei, ei + E, cursor, offs, deg,
                                                           rank, desc, nbrrank, kN, E);
    // node5: per-row 2-path accumulation
    paths_row_kernel<<<kN, 256, (size_t)kN * 4 + 2048, stream>>>(idx_list, offs, desc,
                                                                 nbrrank, out_ung, kN);
}